// Round 2
// baseline (1078.078 us; speedup 1.0000x reference)
//
#include <hip/hip_runtime.h>
#include <stdint.h>

#define NPTS 262144
#define KOFF 27
#define EPS 1e-5f

typedef __attribute__((ext_vector_type(8))) short short8;
typedef __attribute__((ext_vector_type(4))) float floatx4;

__device__ __forceinline__ floatx4 mfma16(short8 a, short8 b, floatx4 c) {
    return __builtin_amdgcn_mfma_f32_16x16x32_bf16(a, b, c, 0, 0, 0);
}

__device__ __forceinline__ uint16_t f2bf(float f) {
    union { float f; uint32_t u; } v; v.f = f;
    return (uint16_t)((v.u + 0x7FFFu + ((v.u >> 16) & 1u)) >> 16);
}

__device__ __forceinline__ float bf2f(uint16_t b) {
    union { uint32_t u; float f; } v; v.u = ((uint32_t)b) << 16; return v.f;
}

// ---------------------------------------------------------------- prep
__global__ void k_prep(const float* __restrict__ W1a, const float* __restrict__ W3,
                       const float* __restrict__ W1b, uint16_t* __restrict__ w1aT,
                       uint16_t* __restrict__ w3T, uint16_t* __restrict__ w1bT,
                       float* __restrict__ stats) {
    int t = blockIdx.x * 256 + threadIdx.x;
    int stride = gridDim.x * 256;
    for (int i = t; i < 64 * 256; i += stride) {        // w1aT[n*256+k] = W1a[k*64+n]
        int n = i >> 8, k = i & 255;
        w1aT[i] = f2bf(W1a[k * 64 + n]);
    }
    for (int i = t; i < KOFF * 64 * 64; i += stride) {  // w3T[kk][o*64+in] = W3[kk][in][o]
        int kk = i >> 12; int r = i & 4095; int o = r >> 6; int in_ = r & 63;
        w3T[i] = f2bf(W3[kk * 4096 + in_ * 64 + o]);
    }
    for (int i = t; i < 256 * 64; i += stride) {        // w1bT[n*64+k] = W1b[k*256+n]
        int n = i >> 6, k = i & 63;
        w1bT[i] = f2bf(W1b[k * 256 + n]);
    }
    for (int i = t; i < 64 * 768; i += stride) stats[i] = 0.f;
}

// ---------------------------------------------------------------- idx transpose
// idxT[k][n] = nidx[n][k]; coalesced read + coalesced write via LDS.
__global__ __launch_bounds__(256) void k_tidx(const int* __restrict__ nidx,
                                              int* __restrict__ idxT) {
    __shared__ int s[256 * KOFF];
    const int t = threadIdx.x;
    const size_t base = (size_t)blockIdx.x * 256;
    const int* src = nidx + base * KOFF;
    for (int j = t; j < 256 * KOFF; j += 256) s[j] = src[j];
    __syncthreads();
#pragma unroll
    for (int k = 0; k < KOFF; ++k)          // stride-27 LDS read: coprime w/32, conflict-free
        idxT[(size_t)k * NPTS + base + t] = s[t * KOFF + k];
}

// ---------------------------------------------------------------- gemm1
// y1 = x @ W1a (bf16 out), + BN1 stats. 64 pts/block.
__global__ __launch_bounds__(256) void k_gemm1(const float* __restrict__ x,
        const uint16_t* __restrict__ w1aT, uint16_t* __restrict__ ybf,
        float* __restrict__ stats) {
    __shared__ uint16_t xs[64 * 264];   // pad 256->264: 2-way alias (free)
    __shared__ float ssum[64], ssq[64];
    const int t = threadIdx.x;
    const int base = blockIdx.x * 64;
    const float4* xv = (const float4*)(x + (size_t)base * 256);
#pragma unroll
    for (int i = 0; i < 16; ++i) {
        int f = t + 256 * i;
        int r = f >> 6, c4 = f & 63;
        float4 v = xv[f];
        uint32_t lo = (uint32_t)f2bf(v.x) | ((uint32_t)f2bf(v.y) << 16);
        uint32_t hi = (uint32_t)f2bf(v.z) | ((uint32_t)f2bf(v.w) << 16);
        uint32_t* dst = (uint32_t*)&xs[r * 264 + c4 * 4];
        dst[0] = lo; dst[1] = hi;
    }
    if (t < 64) { ssum[t] = 0.f; ssq[t] = 0.f; }
    __syncthreads();
    const int wave = t >> 6, lane = t & 63;
    const int m = lane & 15, quad = lane >> 4;
    floatx4 zero = {0.f, 0.f, 0.f, 0.f};
    floatx4 acc[4] = {zero, zero, zero, zero};
    const uint16_t* arow = &xs[(wave * 16 + m) * 264 + quad * 8];
#pragma unroll
    for (int ks = 0; ks < 8; ++ks) {
        short8 a = *(const short8*)(arow + ks * 32);
#pragma unroll
        for (int nf = 0; nf < 4; ++nf) {
            short8 b = *(const short8*)(w1aT + (nf * 16 + m) * 256 + ks * 32 + quad * 8);
            acc[nf] = mfma16(a, b, acc[nf]);
        }
    }
    const int bank = blockIdx.x & 63;
#pragma unroll
    for (int nf = 0; nf < 4; ++nf) {
        float s = 0.f, q = 0.f;
#pragma unroll
        for (int r = 0; r < 4; ++r) {
            float v = acc[nf][r];
            s += v; q += v * v;
        }
        s += __shfl_xor(s, 16); q += __shfl_xor(q, 16);
        s += __shfl_xor(s, 32); q += __shfl_xor(q, 32);
        if (quad == 0) { atomicAdd(&ssum[nf * 16 + m], s); atomicAdd(&ssq[nf * 16 + m], q); }
    }
    // transpose acc -> xs (bf16, [pt][ch]); each wave touches only its own rows
#pragma unroll
    for (int nf = 0; nf < 4; ++nf) {
#pragma unroll
        for (int r = 0; r < 4; ++r) {
            float v = acc[nf][r];
            float pv = __shfl_xor(v, 1);
            if ((lane & 1) == 0) {
                int pt = wave * 16 + quad * 4 + r;
                int ch = nf * 16 + m;
                uint32_t pk = (uint32_t)f2bf(v) | ((uint32_t)f2bf(pv) << 16);
                *(uint32_t*)&xs[pt * 264 + ch] = pk;
            }
        }
    }
    __syncthreads();
    if (t < 64) {
        float* sb = stats + bank * 768;
        atomicAdd(&sb[t], ssum[t]); atomicAdd(&sb[64 + t], ssq[t]);
    }
#pragma unroll
    for (int i = 0; i < 2; ++i) {
        int G = t + 256 * i;
        int row = G >> 3, g = G & 7;
        uint4 v = *(const uint4*)&xs[row * 264 + g * 8];
        *(uint4*)(ybf + ((size_t)(base + row)) * 64 + g * 8) = v;
    }
}

// ---------------------------------------------------------------- BN finalize
__global__ void k_fin(const float* __restrict__ stats, const float* __restrict__ g,
                      const float* __restrict__ bta, float* __restrict__ consts,
                      int nch, int soff, int coff) {
    int c = blockIdx.x * blockDim.x + threadIdx.x;
    if (c >= nch) return;
    float s = 0.f, q = 0.f;
    for (int b = 0; b < 64; ++b) {
        s += stats[b * 768 + soff + c];
        q += stats[b * 768 + soff + nch + c];
    }
    float mean = s / (float)NPTS;
    float var = q / (float)NPTS - mean * mean;
    float sc = g[c] * rsqrtf(var + EPS);
    consts[coff + c] = sc;
    consts[coff + nch + c] = bta[c] - mean * sc;
}

// ---------------------------------------------------------------- bn+relu -> bf16
__global__ __launch_bounds__(256) void k_bnrelu(const uint16_t* __restrict__ ybf,
        const float* __restrict__ consts, uint16_t* __restrict__ h1) {
    __shared__ float cf[128];
    const int t = threadIdx.x;
    if (t < 128) cf[t] = consts[t];
    __syncthreads();
    size_t off = ((size_t)blockIdx.x * 256 + t) * 8;
    uint4 v = *(const uint4*)(ybf + off);
    int cb = (int)(off & 63);
    uint32_t w[4] = {v.x, v.y, v.z, v.w};
    union { uint16_t u[8]; uint4 q; } r;
#pragma unroll
    for (int i = 0; i < 4; ++i) {
        float f0 = bf2f((uint16_t)(w[i] & 0xffffu));
        float f1 = bf2f((uint16_t)(w[i] >> 16));
        int c = cb + i * 2;
        float u0 = f0 * cf[c] + cf[64 + c];
        float u1 = f1 * cf[c + 1] + cf[64 + c + 1];
        r.u[i * 2]     = f2bf(u0 > 0.f ? u0 : 0.f);
        r.u[i * 2 + 1] = f2bf(u1 > 0.f ? u1 : 0.f);
    }
    *(uint4*)(h1 + off) = r.q;
}

// ---------------------------------------------------------------- conv3
// y2[n] = sum_k h1[nbrT[k,n]] @ W3[k], + BN2 stats. 256 pts/block,
// XOR-swizzled LDS (conflict-free b128 r/w), register prefetch of k+1.
__global__ __launch_bounds__(256, 3) void k_conv3(const uint16_t* __restrict__ h1,
        const int* __restrict__ idxT, const uint16_t* __restrict__ w3T,
        uint16_t* __restrict__ y2, float* __restrict__ stats) {
    __shared__ uint16_t as_[256 * 64];  // 32 KB, row=128B, granule-swizzled
    __shared__ uint16_t bs[64 * 64];    // 8 KB
    __shared__ float ssum[64], ssq[64];
    const int t = threadIdx.x;
    const int base = blockIdx.x * 256;
    if (t < 64) { ssum[t] = 0.f; ssq[t] = 0.f; }
    const int wave = t >> 6, lane = t & 63;
    const int m = lane & 15, quad = lane >> 4;
    const int sx = m & 7;               // row&7 for all this lane's A/B rows
    floatx4 acc[4][4];
#pragma unroll
    for (int a = 0; a < 4; ++a)
#pragma unroll
        for (int b = 0; b < 4; ++b) acc[a][b] = (floatx4){0.f, 0.f, 0.f, 0.f};
    uint4 ga[8], wb0, wb1;
    {
        int gi = idxT[base + t];
        const uint4* gs = (const uint4*)(h1 + (size_t)gi * 64);
#pragma unroll
        for (int g = 0; g < 8; ++g) ga[g] = gs[g];
        const uint4* ws = (const uint4*)w3T;
        wb0 = ws[t]; wb1 = ws[t + 256];
    }
    char* asb = (char*)as_;
    char* bsb = (char*)bs;
    const int tx = t & 7;
    for (int k = 0; k < KOFF; ++k) {
        __syncthreads();                 // prev iter's LDS reads done
#pragma unroll
        for (int g = 0; g < 8; ++g)
            *(uint4*)(asb + t * 128 + ((g ^ tx) << 4)) = ga[g];
        {
            int r0 = t >> 3;
            *(uint4*)(bsb + r0 * 128 + ((tx ^ (r0 & 7)) << 4)) = wb0;
            int r1 = (t + 256) >> 3;
            *(uint4*)(bsb + r1 * 128 + ((tx ^ (r1 & 7)) << 4)) = wb1;
        }
        __syncthreads();
        if (k + 1 < KOFF) {              // prefetch next offset (overlaps MFMAs)
            int gi = idxT[(size_t)(k + 1) * NPTS + base + t];
            const uint4* gs = (const uint4*)(h1 + (size_t)gi * 64);
#pragma unroll
            for (int g = 0; g < 8; ++g) ga[g] = gs[g];
            const uint4* ws = (const uint4*)(w3T + (k + 1) * 4096);
            wb0 = ws[t]; wb1 = ws[t + 256];
        }
#pragma unroll
        for (int ks = 0; ks < 2; ++ks) {
            int gq = ks * 4 + quad;
            short8 bfr[4];
#pragma unroll
            for (int nf = 0; nf < 4; ++nf) {
                int rn = nf * 16 + m;
                bfr[nf] = *(const short8*)(bsb + rn * 128 + ((gq ^ sx) << 4));
            }
#pragma unroll
            for (int mt = 0; mt < 4; ++mt) {
                int r = wave * 64 + mt * 16 + m;
                short8 a = *(const short8*)(asb + r * 128 + ((gq ^ sx) << 4));
#pragma unroll
                for (int nf = 0; nf < 4; ++nf)
                    acc[mt][nf] = mfma16(a, bfr[nf], acc[mt][nf]);
            }
        }
    }
    const int bank = blockIdx.x & 63;
#pragma unroll
    for (int nf = 0; nf < 4; ++nf) {
        float s = 0.f, q = 0.f;
#pragma unroll
        for (int mt = 0; mt < 4; ++mt) {
#pragma unroll
            for (int r = 0; r < 4; ++r) {
                float v = acc[mt][nf][r];
                int pt = base + wave * 64 + mt * 16 + quad * 4 + r;
                y2[(size_t)pt * 64 + nf * 16 + m] = f2bf(v);
                s += v; q += v * v;
            }
        }
        s += __shfl_xor(s, 16); q += __shfl_xor(q, 16);
        s += __shfl_xor(s, 32); q += __shfl_xor(q, 32);
        if (quad == 0) { atomicAdd(&ssum[nf * 16 + m], s); atomicAdd(&ssq[nf * 16 + m], q); }
    }
    __syncthreads();
    if (t < 64) {
        atomicAdd(&stats[bank * 768 + 128 + t], ssum[t]);
        atomicAdd(&stats[bank * 768 + 192 + t], ssq[t]);
    }
}

// ---------------------------------------------------------------- gemm3 (stats pass)
// h2 = bf16(relu(bn2(y2))); y3 = h2 @ W1b for BN3 stats only.
__global__ __launch_bounds__(256) void k_gemm3(const uint16_t* __restrict__ y2,
        const float* __restrict__ consts, const uint16_t* __restrict__ w1bT,
        uint16_t* __restrict__ h2, float* __restrict__ stats) {
    __shared__ uint16_t as_[64 * 72];
    __shared__ uint16_t bs[256 * 72];
    __shared__ float ssum[256], ssq[256];
    __shared__ float cf[128];
    const int t = threadIdx.x;
    const int base = blockIdx.x * 64;
    if (t < 128) cf[t] = consts[128 + t];
    ssum[t] = 0.f; ssq[t] = 0.f;
    const uint4* wsrc = (const uint4*)w1bT;
#pragma unroll
    for (int i = 0; i < 8; ++i) {
        int c = t + 256 * i;
        uint4 v = wsrc[c];
        *(uint4*)&bs[(c >> 3) * 72 + (c & 7) * 8] = v;
    }
    __syncthreads();   // cf visible
#pragma unroll
    for (int i = 0; i < 2; ++i) {
        int G = t + 256 * i;
        int row = G >> 3, g = G & 7;
        uint4 v = *(const uint4*)(y2 + (size_t)(base + row) * 64 + g * 8);
        uint32_t w[4] = {v.x, v.y, v.z, v.w};
        union { uint16_t u[8]; uint4 q; } r;
#pragma unroll
        for (int j = 0; j < 4; ++j) {
            int c = g * 8 + j * 2;
            float f0 = bf2f((uint16_t)(w[j] & 0xffffu));
            float f1 = bf2f((uint16_t)(w[j] >> 16));
            float u0 = f0 * cf[c] + cf[64 + c];
            float u1 = f1 * cf[c + 1] + cf[64 + c + 1];
            r.u[j * 2]     = f2bf(u0 > 0.f ? u0 : 0.f);
            r.u[j * 2 + 1] = f2bf(u1 > 0.f ? u1 : 0.f);
        }
        *(uint4*)&as_[row * 72 + g * 8] = r.q;
        *(uint4*)(h2 + (size_t)(base + row) * 64 + g * 8) = r.q;
    }
    __syncthreads();
    const int wave = t >> 6, lane = t & 63;
    const int m = lane & 15, quad = lane >> 4;
    floatx4 zero = {0.f, 0.f, 0.f, 0.f};
    floatx4 acc[16];
#pragma unroll
    for (int i = 0; i < 16; ++i) acc[i] = zero;
    const uint16_t* arow = &as_[(wave * 16 + m) * 72 + quad * 8];
#pragma unroll
    for (int ks = 0; ks < 2; ++ks) {
        short8 a = *(const short8*)(arow + ks * 32);
#pragma unroll
        for (int nf = 0; nf < 16; ++nf) {
            short8 b = *(const short8*)&bs[(nf * 16 + m) * 72 + ks * 32 + quad * 8];
            acc[nf] = mfma16(a, b, acc[nf]);
        }
    }
    const int bank = blockIdx.x & 63;
#pragma unroll
    for (int nf = 0; nf < 16; ++nf) {
        float s = 0.f, q = 0.f;
#pragma unroll
        for (int rr = 0; rr < 4; ++rr) { float v = acc[nf][rr]; s += v; q += v * v; }
        s += __shfl_xor(s, 16); q += __shfl_xor(q, 16);
        s += __shfl_xor(s, 32); q += __shfl_xor(q, 32);
        if (quad == 0) { atomicAdd(&ssum[nf * 16 + m], s); atomicAdd(&ssq[nf * 16 + m], q); }
    }
    __syncthreads();
    atomicAdd(&stats[bank * 768 + 256 + t], ssum[t]);
    atomicAdd(&stats[bank * 768 + 512 + t], ssq[t]);
}

// ---------------------------------------------------------------- final
// Recompute y3 = h2 @ W1b, out = relu(bn3(y3) + x).
__global__ __launch_bounds__(256) void k_final(const uint16_t* __restrict__ h2,
        const uint16_t* __restrict__ w1bT, const float* __restrict__ consts,
        const float* __restrict__ x, float* __restrict__ out) {
    __shared__ uint16_t as_[64 * 72];
    __shared__ uint16_t bs[256 * 72];
    const int t = threadIdx.x;
    const int base = blockIdx.x * 64;
    const uint4* wsrc = (const uint4*)w1bT;
#pragma unroll
    for (int i = 0; i < 8; ++i) {
        int c = t + 256 * i;
        uint4 v = wsrc[c];
        *(uint4*)&bs[(c >> 3) * 72 + (c & 7) * 8] = v;
    }
    const uint4* hsrc = (const uint4*)(h2 + (size_t)base * 64);
#pragma unroll
    for (int i = 0; i < 2; ++i) {
        int c = t + 256 * i;
        uint4 v = hsrc[c];
        *(uint4*)&as_[(c >> 3) * 72 + (c & 7) * 8] = v;
    }
    __syncthreads();
    const int wave = t >> 6, lane = t & 63;
    const int m = lane & 15, quad = lane >> 4;
    floatx4 zero = {0.f, 0.f, 0.f, 0.f};
    floatx4 acc[16];
#pragma unroll
    for (int i = 0; i < 16; ++i) acc[i] = zero;
    const uint16_t* arow = &as_[(wave * 16 + m) * 72 + quad * 8];
#pragma unroll
    for (int ks = 0; ks < 2; ++ks) {
        short8 a = *(const short8*)(arow + ks * 32);
#pragma unroll
        for (int nf = 0; nf < 16; ++nf) {
            short8 b = *(const short8*)&bs[(nf * 16 + m) * 72 + ks * 32 + quad * 8];
            acc[nf] = mfma16(a, b, acc[nf]);
        }
    }
#pragma unroll
    for (int nf = 0; nf < 16; ++nf) {
        int ch = nf * 16 + m;
        float sc = consts[256 + ch], sh = consts[512 + ch];
#pragma unroll
        for (int r = 0; r < 4; ++r) {
            int pt = base + wave * 16 + quad * 4 + r;
            size_t o = (size_t)pt * 256 + ch;
            float v = acc[nf][r] * sc + sh + x[o];
            out[o] = v > 0.f ? v : 0.f;
        }
    }
}

// ---------------------------------------------------------------- launch
extern "C" void kernel_launch(void* const* d_in, const int* in_sizes, int n_in,
                              void* d_out, int out_size, void* d_ws, size_t ws_size,
                              hipStream_t stream) {
    const float* x   = (const float*)d_in[0];
    const int* nidx  = (const int*)d_in[1];
    const float* W1a = (const float*)d_in[2];
    const float* g1a = (const float*)d_in[3];
    const float* b1a = (const float*)d_in[4];
    const float* W3  = (const float*)d_in[5];
    const float* g3  = (const float*)d_in[6];
    const float* b3  = (const float*)d_in[7];
    const float* W1b = (const float*)d_in[8];
    const float* g1b = (const float*)d_in[9];
    const float* b1b = (const float*)d_in[10];
    float* out = (float*)d_out;

    // workspace layout (~163 MB)
    uint16_t* ybf  = (uint16_t*)d_ws;                   // N*64 bf16
    uint16_t* h1   = ybf + (size_t)NPTS * 64;           // N*64 bf16
    uint16_t* y2   = h1 + (size_t)NPTS * 64;            // N*64 bf16
    uint16_t* h2   = y2 + (size_t)NPTS * 64;            // N*64 bf16
    uint16_t* w1aT = h2 + (size_t)NPTS * 64;            // 64*256
    uint16_t* w3T  = w1aT + 64 * 256;                   // 27*64*64
    uint16_t* w1bT = w3T + KOFF * 64 * 64;              // 256*64
    int* idxT      = (int*)(w1bT + 256 * 64);           // 27*N
    float* stats   = (float*)(idxT + (size_t)KOFF * NPTS); // 64 banks * 768
    float* consts  = stats + 64 * 768;                  // 768

    k_prep<<<64, 256, 0, stream>>>(W1a, W3, W1b, w1aT, w3T, w1bT, stats);
    k_tidx<<<NPTS / 256, 256, 0, stream>>>(nidx, idxT);
    k_gemm1<<<NPTS / 64, 256, 0, stream>>>(x, w1aT, ybf, stats);
    k_fin<<<1, 64, 0, stream>>>(stats, g1a, b1a, consts, 64, 0, 0);
    k_bnrelu<<<NPTS * 64 / (256 * 8), 256, 0, stream>>>(ybf, consts, h1);
    k_conv3<<<NPTS / 256, 256, 0, stream>>>(h1, idxT, w3T, y2, stats);
    k_fin<<<1, 64, 0, stream>>>(stats, g3, b3, consts, 64, 128, 128);
    k_gemm3<<<NPTS / 64, 256, 0, stream>>>(y2, consts, w1bT, h2, stats);
    k_fin<<<1, 256, 0, stream>>>(stats, g1b, b1b, consts, 256, 256, 256);
    k_final<<<NPTS / 64, 256, 0, stream>>>(h2, w1bT, consts, x, out);
}